// Round 9
// baseline (345.779 us; speedup 1.0000x reference)
//
#include <hip/hip_runtime.h>
#include <hip/hip_cooperative_groups.h>
#include <math.h>

namespace cg = cooperative_groups;

// ----------------------------------------------------------------------------
// SingleHeadSelfAttention, N=8192, DIM=128, fp32 in/out.
// ONE cooperative kernel (256 WGs x 512 thr, 1 WG/CU, grid.sync between
// phases) fusing:
//   phase 1 (proj):   Q (pre-scaled by scale*log2e), K row-major, V^T.
//                     192 WGs x one 128-row tile of one z; inline fp32->bf16.
//   phase 2 (attn):   r7 body verbatim: flash attention, no running max
//                     (scores bounded), P LDS-free (cvt_pk + permlane32/16),
//                     K/V double-buffered, reg-prefetch staging, 1 barrier/it.
//   phase 3 (combine): sum 8 chunk partials, normalize, 32x32x16 GEMM @ Wo^T.
// r8 fix: no brace-initialized LDS pointer arrays (hipcc can't emit the
// addrspacecast aggregate); use direct offset arithmetic instead.
// ----------------------------------------------------------------------------

typedef __bf16 bf16x8 __attribute__((ext_vector_type(8)));
typedef float f32x4 __attribute__((ext_vector_type(4)));
typedef float f32x16 __attribute__((ext_vector_type(16)));
typedef unsigned int u32x4 __attribute__((ext_vector_type(4)));
typedef unsigned int u32x2 __attribute__((ext_vector_type(2)));
typedef unsigned short us16;

#define NTOK 8192
#define CHUNKS 8
#define KTILE (64 * 136)
#define VTILE (128 * 72)

// scale * log2(e);  scale = 1/sqrt(128)
static constexpr float SCALE_L2E = 0.08838834764831845f * 1.4426950408889634f;

__device__ __forceinline__ unsigned f2bf_u(float x) {
    unsigned u = __builtin_bit_cast(unsigned, x);
    return (u + 0x7FFFu + ((u >> 16) & 1u)) >> 16;   // RNE, no NaN inputs here
}

__device__ __forceinline__ unsigned pk_bf16(float x, float y) {
    unsigned a = __builtin_bit_cast(unsigned, x) + 0x8000u;
    unsigned b = __builtin_bit_cast(unsigned, y) + 0x8000u;
#if __has_builtin(__builtin_amdgcn_perm)
    return __builtin_amdgcn_perm(b, a, 0x07060302u);  // {b.hi16 : a.hi16}
#else
    return (a >> 16) | (b & 0xFFFF0000u);
#endif
}

// single-instruction RNE pack of two fp32 -> bf16x2 (low = x, high = y)
__device__ __forceinline__ unsigned cvtpk_bf16(float x, float y) {
    unsigned r;
    asm("v_cvt_pk_bf16_f32 %0, %1, %2" : "=v"(r) : "v"(x), "v"(y));
    return r;
}

// v_permlane32_swap_b32 (validated r1):
//   a' = [a.lanes0-31 | b.lanes0-31], b' = [a.lanes32-63 | b.lanes32-63]
__device__ __forceinline__ void plswap(unsigned& a, unsigned& b) {
    asm("v_permlane32_swap_b32 %0, %1" : "+v"(a), "+v"(b));
}

// v_permlane16_swap_b32: a.g1 <-> b.g0, a.g3 <-> b.g2  (g = 16-lane group)
__device__ __forceinline__ void pl16swap(unsigned& a, unsigned& b) {
    asm("v_permlane16_swap_b32 %0, %1" : "+v"(a), "+v"(b));
}

__device__ __forceinline__ float fexp2(float x) {
#if __has_builtin(__builtin_amdgcn_exp2f)
    return __builtin_amdgcn_exp2f(x);
#else
    return exp2f(x);
#endif
}

__device__ __forceinline__ bf16x8 ld_frag(const us16* p) {
    u32x4 u = *reinterpret_cast<const u32x4*>(p);
    return __builtin_bit_cast(bf16x8, u);
}

// load 8 consecutive fp32 and RNE-convert to a bf16x8 fragment
__device__ __forceinline__ bf16x8 cvt_frag(const float* p) {
    f32x4 a = *reinterpret_cast<const f32x4*>(p);
    f32x4 b = *reinterpret_cast<const f32x4*>(p + 4);
    u32x4 o;
    o[0] = f2bf_u(a[0]) | (f2bf_u(a[1]) << 16);
    o[1] = f2bf_u(a[2]) | (f2bf_u(a[3]) << 16);
    o[2] = f2bf_u(b[0]) | (f2bf_u(b[1]) << 16);
    o[3] = f2bf_u(b[2]) | (f2bf_u(b[3]) << 16);
    return __builtin_bit_cast(bf16x8, o);
}

// ----------------------------------------------------------- fused kernel
__global__ __launch_bounds__(512, 2) void fused(
    const float* __restrict__ x,
    const float* __restrict__ wq, const float* __restrict__ bq,
    const float* __restrict__ wk, const float* __restrict__ bk,
    const float* __restrict__ wv, const float* __restrict__ bv,
    const float* __restrict__ Wo, const float* __restrict__ bo,
    us16* __restrict__ Qb, us16* __restrict__ Kb, us16* __restrict__ Vt,
    float* __restrict__ Opart, float* __restrict__ Lpart,
    float* __restrict__ out)
{
    // 2x K tile [64x136] + 2x V^T tile [128x72] = 71680 B; aliased per phase
    __shared__ us16 smem[2 * KTILE + 2 * VTILE];
    __shared__ float ldsL[32];

    cg::grid_group grid = cg::this_grid();

    int bid = blockIdx.x;
    int tid = threadIdx.x, w = tid >> 6, lane = tid & 63;
    int quad = lane >> 4, l15 = lane & 15;

    // ==================== phase 1: QKV projection ====================
    // 192 WGs: z = bid>>6 (0:Q 1:K 2:V), tile = bid&63 (128 rows, 8 waves x 16)
    if (bid < 192) {
        int z = bid >> 6;
        int tile = bid & 63;
        const float* W = z == 0 ? wq : z == 1 ? wk : wv;
        const float* bias = z == 0 ? bq : z == 1 ? bk : bv;
        float osc = z == 0 ? SCALE_L2E : 1.0f;
        int rbase = tile * 128 + w * 16;

        bf16x8 af[4];
#pragma unroll
        for (int ks = 0; ks < 4; ++ks)
            af[ks] = cvt_frag(x + (rbase + l15) * 128 + ks * 32 + quad * 8);

        f32x4 acc[8];
#pragma unroll
        for (int nt = 0; nt < 8; ++nt) acc[nt] = f32x4{0.f, 0.f, 0.f, 0.f};

#pragma unroll
        for (int nt = 0; nt < 8; ++nt) {
#pragma unroll
            for (int ks = 0; ks < 4; ++ks) {
                bf16x8 bf = cvt_frag(W + (nt * 16 + l15) * 128 + ks * 32 + quad * 8);
                acc[nt] = __builtin_amdgcn_mfma_f32_16x16x32_bf16(af[ks], bf, acc[nt], 0, 0, 0);
            }
        }

        if (z < 2) {
            // row-major out: per-wave LDS transpose tile -> 16B coalesced stores
            us16* T = smem + w * (16 * 136);
            us16* Out = z == 0 ? Qb : Kb;
#pragma unroll
            for (int nt = 0; nt < 8; ++nt) {
                float bb = bias[nt * 16 + l15];
#pragma unroll
                for (int r = 0; r < 4; ++r)
                    T[(quad * 4 + r) * 136 + nt * 16 + l15] =
                        (us16)f2bf_u((acc[nt][r] + bb) * osc);
            }
            // wave-private tile: drain LDS writes before readback (no barrier)
            asm volatile("s_waitcnt lgkmcnt(0)" ::: "memory");
            __builtin_amdgcn_sched_barrier(0);
            int row = lane >> 2, seg = lane & 3;   // 4 lanes per row, 64B each
            const us16* src = T + row * 136 + seg * 32;
            us16* dst = Out + (rbase + row) * 128 + seg * 32;
#pragma unroll
            for (int c = 0; c < 4; ++c)
                *reinterpret_cast<u32x4*>(dst + c * 8) =
                    *reinterpret_cast<const u32x4*>(src + c * 8);
        } else {
            // V^T out: columns rbase+quad*4..+4 of rows d = nt*16+l15
#pragma unroll
            for (int nt = 0; nt < 8; ++nt) {
                float bb = bias[nt * 16 + l15];
                int d = nt * 16 + l15, r0 = rbase + quad * 4;
                u32x2 pk;
                pk[0] = f2bf_u(acc[nt][0] + bb) | (f2bf_u(acc[nt][1] + bb) << 16);
                pk[1] = f2bf_u(acc[nt][2] + bb) | (f2bf_u(acc[nt][3] + bb) << 16);
                *reinterpret_cast<u32x2*>(Vt + d * NTOK + r0) = pk;
            }
        }
    }

    __threadfence();
    grid.sync();

    // ==================== phase 2: flash attention ====================
    // r7 body: 256 WGs = 32 q-tiles (256 rows) x 8 chunks; wave owns 32 rows.
    {
        us16* ldsK0 = smem;                 // [2][64*136]
        us16* ldsV0 = smem + 2 * KTILE;     // [2][128*72]

        int qtile = bid >> 3, chunk = bid & 7;
        int qb0 = qtile * 256 + w * 32;
        int k0 = chunk * 1024;

        bf16x8 qf[2][4];
#pragma unroll
        for (int mt = 0; mt < 2; ++mt)
#pragma unroll
            for (int ks = 0; ks < 4; ++ks)
                qf[mt][ks] = ld_frag(Qb + (qb0 + mt * 16 + l15) * 128 + ks * 32 + quad * 8);

        f32x4 o[2][8];
#pragma unroll
        for (int mt = 0; mt < 2; ++mt)
#pragma unroll
            for (int dt = 0; dt < 8; ++dt) o[mt][dt] = f32x4{0.f, 0.f, 0.f, 0.f};

        f32x4 lacc[2];
        lacc[0] = f32x4{0.f, 0.f, 0.f, 0.f};
        lacc[1] = f32x4{0.f, 0.f, 0.f, 0.f};

        u32x4 onesu;
        onesu[0] = onesu[1] = onesu[2] = onesu[3] = 0x3F803F80u;  // bf16 1.0 x8
        bf16x8 ones = __builtin_bit_cast(bf16x8, onesu);

        // prologue: stage tile 0 into buffer 0 (512 thr x 16B x 2 passes/tile)
#pragma unroll
        for (int c = 0; c < 2; ++c) {
            int idx = tid + c * 512, r = idx >> 4, cc = idx & 15;
            *reinterpret_cast<u32x4*>(ldsK0 + r * 136 + cc * 8) =
                *reinterpret_cast<const u32x4*>(Kb + (k0 + r) * 128 + cc * 8);
        }
#pragma unroll
        for (int c = 0; c < 2; ++c) {
            int idx = tid + c * 512, r = idx >> 3, cc = idx & 7;
            *reinterpret_cast<u32x4*>(ldsV0 + r * 72 + cc * 8) =
                *reinterpret_cast<const u32x4*>(Vt + (size_t)r * NTOK + k0 + cc * 8);
        }
        __syncthreads();

        for (int it = 0; it < 16; ++it) {
            int cur = it & 1;
            const us16* K_ = ldsK0 + cur * KTILE;
            const us16* V_ = ldsV0 + cur * VTILE;

            // issue next tile's global loads (fenced at iter top)
            u32x4 kreg[2], vreg[2];
            if (it < 15) {
                int kk = k0 + (it + 1) * 64;
#pragma unroll
                for (int c = 0; c < 2; ++c) {
                    int idx = tid + c * 512, r = idx >> 4, cc = idx & 15;
                    kreg[c] = *reinterpret_cast<const u32x4*>(Kb + (kk + r) * 128 + cc * 8);
                }
#pragma unroll
                for (int c = 0; c < 2; ++c) {
                    int idx = tid + c * 512, r = idx >> 3, cc = idx & 7;
                    vreg[c] = *reinterpret_cast<const u32x4*>(Vt + (size_t)r * NTOK + kk + cc * 8);
                }
                __builtin_amdgcn_sched_barrier(0);
            }

            // S^T = K Q^T: lane (quad,l15) reg r = S[m=l15][n=nt*16+quad*4+r]
            f32x4 s[2][4];
#pragma unroll
            for (int mt = 0; mt < 2; ++mt)
#pragma unroll
                for (int nt = 0; nt < 4; ++nt) s[mt][nt] = f32x4{0.f, 0.f, 0.f, 0.f};

            __builtin_amdgcn_s_setprio(1);
#pragma unroll
            for (int nt = 0; nt < 4; ++nt) {
#pragma unroll
                for (int ks = 0; ks < 4; ++ks) {
                    bf16x8 kf = ld_frag(K_ + (nt * 16 + l15) * 136 + ks * 32 + quad * 8);
                    s[0][nt] = __builtin_amdgcn_mfma_f32_16x16x32_bf16(kf, qf[0][ks], s[0][nt], 0, 0, 0);
                    s[1][nt] = __builtin_amdgcn_mfma_f32_16x16x32_bf16(kf, qf[1][ks], s[1][nt], 0, 0, 0);
                }
            }
            __builtin_amdgcn_s_setprio(0);

            // P = exp2(S^T); cvt_pk pairs; permlane reshape -> PV A-frags
            bf16x8 afP[2][2];
#pragma unroll
            for (int mt = 0; mt < 2; ++mt) {
                unsigned W[4][2];
#pragma unroll
                for (int nt = 0; nt < 4; ++nt) {
                    float p0 = fexp2(s[mt][nt][0]);
                    float p1 = fexp2(s[mt][nt][1]);
                    float p2 = fexp2(s[mt][nt][2]);
                    float p3 = fexp2(s[mt][nt][3]);
                    W[nt][0] = cvtpk_bf16(p0, p1);
                    W[nt][1] = cvtpk_bf16(p2, p3);
                }
#pragma unroll
                for (int k2 = 0; k2 < 2; ++k2) {
                    u32x4 f;
                    {
                        unsigned X = W[2 * k2][0], Y = W[2 * k2 + 1][0];
                        plswap(X, Y); pl16swap(X, Y);
                        f[0] = X; f[2] = Y;
                    }
                    {
                        unsigned X = W[2 * k2][1], Y = W[2 * k2 + 1][1];
                        plswap(X, Y); pl16swap(X, Y);
                        f[1] = X; f[3] = Y;
                    }
                    afP[mt][k2] = __builtin_bit_cast(bf16x8, f);
                }
            }

            // l += P @ ones;  O += P V
            lacc[0] = __builtin_amdgcn_mfma_f32_16x16x32_bf16(afP[0][0], ones, lacc[0], 0, 0, 0);
            lacc[0] = __builtin_amdgcn_mfma_f32_16x16x32_bf16(afP[0][1], ones, lacc[0], 0, 0, 0);
            lacc[1] = __builtin_amdgcn_mfma_f32_16x16x32_bf16(afP[1][0], ones, lacc[1], 0, 0, 0);
            lacc[1] = __builtin_amdgcn_mfma_f32_16x16x32_bf16(afP[1][1], ones, lacc[1], 0, 0, 0);

            __builtin_amdgcn_s_setprio(1);
#pragma unroll
            for (int dt = 0; dt < 8; ++dt) {
#pragma unroll
                for (int k2 = 0; k2 < 2; ++k2) {
                    bf16x8 bv = ld_frag(V_ + (dt * 16 + l15) * 72 + k2 * 32 + quad * 8);
                    o[0][dt] = __builtin_amdgcn_mfma_f32_16x16x32_bf16(afP[0][k2], bv, o[0][dt], 0, 0, 0);
                    o[1][dt] = __builtin_amdgcn_mfma_f32_16x16x32_bf16(afP[1][k2], bv, o[1][dt], 0, 0, 0);
                }
            }
            __builtin_amdgcn_s_setprio(0);

            // write prefetched tile into the other buffer, then ONE barrier
            if (it < 15) {
                __builtin_amdgcn_sched_barrier(0);
                us16* Kn = ldsK0 + (cur ^ 1) * KTILE;
                us16* Vn = ldsV0 + (cur ^ 1) * VTILE;
#pragma unroll
                for (int c = 0; c < 2; ++c) {
                    int idx = tid + c * 512, r = idx >> 4, cc = idx & 15;
                    *reinterpret_cast<u32x4*>(Kn + r * 136 + cc * 8) = kreg[c];
                }
#pragma unroll
                for (int c = 0; c < 2; ++c) {
                    int idx = tid + c * 512, r = idx >> 3, cc = idx & 7;
                    *reinterpret_cast<u32x4*>(Vn + r * 72 + cc * 8) = vreg[c];
                }
            }
            __syncthreads();
        }

        // write unnormalized partials
#pragma unroll
        for (int mt = 0; mt < 2; ++mt)
#pragma unroll
            for (int dt = 0; dt < 8; ++dt)
#pragma unroll
                for (int r = 0; r < 4; ++r) {
                    int row = qb0 + mt * 16 + quad * 4 + r;
                    Opart[(size_t)(chunk * NTOK + row) * 128 + dt * 16 + l15] = o[mt][dt][r];
                }
        if (l15 == 0) {
#pragma unroll
            for (int mt = 0; mt < 2; ++mt)
#pragma unroll
                for (int r = 0; r < 4; ++r) {
                    int row = qb0 + mt * 16 + quad * 4 + r;
                    Lpart[chunk * NTOK + row] = lacc[mt][r];
                }
        }
    }

    __threadfence();
    grid.sync();

    // ==================== phase 3: combine + output proj ====================
    // 256 WGs x 32 rows: sum 8 chunk partials, normalize, bf16 -> LDS,
    // 32x32x16 GEMM @ Wo^T (waves 0-3) + bo.
    {
        us16* ldsO = smem;   // 32 x 136
        int r0 = bid * 32;
        int t = tid;

        if (t < 32) {
            float L = 0.f;
#pragma unroll
            for (int c = 0; c < CHUNKS; ++c) L += Lpart[c * NTOK + r0 + t];
            ldsL[t] = 1.0f / L;
        }

        f32x4 acc[2];
        acc[0] = f32x4{0.f, 0.f, 0.f, 0.f};
        acc[1] = f32x4{0.f, 0.f, 0.f, 0.f};

#pragma unroll
        for (int c = 0; c < CHUNKS; ++c) {
            const float* src = Opart + (size_t)(c * NTOK + r0) * 128;
#pragma unroll
            for (int j = 0; j < 2; ++j) {
                f32x4 v = *reinterpret_cast<const f32x4*>(src + j * 2048 + t * 4);
                acc[j] += v;
            }
        }
        __syncthreads();   // ldsL ready (and phase-2 smem reads long done)

#pragma unroll
        for (int j = 0; j < 2; ++j) {
            int flat = j * 2048 + t * 4;
            int row = flat >> 7, col = flat & 127;
            float sc = ldsL[row];
            u32x2 wv;
            wv[0] = pk_bf16(acc[j][0] * sc, acc[j][1] * sc);
            wv[1] = pk_bf16(acc[j][2] * sc, acc[j][3] * sc);
            *reinterpret_cast<u32x2*>(ldsO + row * 136 + col) = wv;
        }
        __syncthreads();

        // GEMM: 32 rows x 128 @ Wo^T; waves 0-3, wave w -> cols [w*32, +32)
        if (w < 4) {
            int l31 = lane & 31, hi = lane >> 5;

            bf16x8 af[8];
#pragma unroll
            for (int ks = 0; ks < 8; ++ks)
                af[ks] = ld_frag(ldsO + l31 * 136 + ks * 16 + hi * 8);

            f32x16 acc2;
#pragma unroll
            for (int r = 0; r < 16; ++r) acc2[r] = 0.f;

#pragma unroll
            for (int ks = 0; ks < 8; ++ks) {
                bf16x8 bfw = cvt_frag(Wo + (w * 32 + l31) * 128 + ks * 16 + hi * 8);
                acc2 = __builtin_amdgcn_mfma_f32_32x32x16_bf16(af[ks], bfw, acc2, 0, 0, 0);
            }

            float bb = bo[w * 32 + l31];
#pragma unroll
            for (int r = 0; r < 16; ++r) {
                int m = (r & 3) + 8 * (r >> 2) + 4 * hi;
                out[(size_t)(r0 + m) * 128 + w * 32 + l31] = acc2[r] + bb;
            }
        }
    }
}

// ------------------------------------------------------------------- launcher
extern "C" void kernel_launch(void* const* d_in, const int* in_sizes, int n_in,
                              void* d_out, int out_size, void* d_ws, size_t ws_size,
                              hipStream_t stream)
{
    const float* x  = (const float*)d_in[0];
    const float* Wq = (const float*)d_in[1];
    const float* bq = (const float*)d_in[2];
    const float* Wk = (const float*)d_in[3];
    const float* bk = (const float*)d_in[4];
    const float* Wv = (const float*)d_in[5];
    const float* bv = (const float*)d_in[6];
    const float* Wo = (const float*)d_in[7];
    const float* bo = (const float*)d_in[8];

    char* ws = (char*)d_ws;
    const size_t MB = 1024 * 1024;
    us16* Qb  = (us16*)(ws + 0 * MB);                   // 2 MB
    us16* Kb  = (us16*)(ws + 2 * MB);                   // 2 MB
    us16* Vt  = (us16*)(ws + 4 * MB);                   // 2 MB
    float* Lp = (float*)(ws + 6 * MB);                  // 256 KB
    float* Op = (float*)(ws + 7 * MB);                  // 32 MB
    float* outp = (float*)d_out;
    // total ws use: 39 MB

    void* args[] = { &x, &Wq, &bq, &Wk, &bk, &Wv, &bv, &Wo, &bo,
                     &Qb, &Kb, &Vt, &Op, &Lp, &outp };
    (void)hipLaunchCooperativeKernel((void*)fused, dim3(256), dim3(512),
                                     args, 0, stream);
}

// Round 10
// 231.522 us; speedup vs baseline: 1.4935x; 1.4935x over previous
//
#include <hip/hip_runtime.h>
#include <math.h>

// ----------------------------------------------------------------------------
// SingleHeadSelfAttention, N=8192, DIM=128, fp32 in/out.
// TWO kernels (r9 lesson: grid.sync costs ~100us on MI355X -- refuted; use
// point-to-point completion counters instead):
//   1. proj_qkv:      r7 verbatim + zeroes the 32 per-qtile counters.
//   2. attn_combine:  r7 attn body verbatim (flash attention, no running max,
//                     P LDS-free via cvt_pk + permlane32/16, K/V double-
//                     buffered, reg-prefetch staging, 1 barrier/iter).
//                     After writing partials: __threadfence + atomicAdd on
//                     cnt[qtile]; the 8th (last) chunk-WG performs combine +
//                     output projection for its 256 rows in-place (8 waves x
//                     32 rows, 32x32x16 GEMM @ Wo^T + bo). Deletes the
//                     combine launch + its dispatch gap; tail overlaps attn.
// ----------------------------------------------------------------------------

typedef __bf16 bf16x8 __attribute__((ext_vector_type(8)));
typedef float f32x4 __attribute__((ext_vector_type(4)));
typedef float f32x16 __attribute__((ext_vector_type(16)));
typedef unsigned int u32x4 __attribute__((ext_vector_type(4)));
typedef unsigned int u32x2 __attribute__((ext_vector_type(2)));
typedef unsigned short us16;

#define NTOK 8192
#define CHUNKS 8
#define KTILE (64 * 136)
#define VTILE (128 * 72)

// scale * log2(e);  scale = 1/sqrt(128)
static constexpr float SCALE_L2E = 0.08838834764831845f * 1.4426950408889634f;

__device__ __forceinline__ unsigned f2bf_u(float x) {
    unsigned u = __builtin_bit_cast(unsigned, x);
    return (u + 0x7FFFu + ((u >> 16) & 1u)) >> 16;   // RNE, no NaN inputs here
}

__device__ __forceinline__ unsigned pk_bf16(float x, float y) {
    unsigned a = __builtin_bit_cast(unsigned, x) + 0x8000u;
    unsigned b = __builtin_bit_cast(unsigned, y) + 0x8000u;
#if __has_builtin(__builtin_amdgcn_perm)
    return __builtin_amdgcn_perm(b, a, 0x07060302u);  // {b.hi16 : a.hi16}
#else
    return (a >> 16) | (b & 0xFFFF0000u);
#endif
}

// single-instruction RNE pack of two fp32 -> bf16x2 (low = x, high = y)
__device__ __forceinline__ unsigned cvtpk_bf16(float x, float y) {
    unsigned r;
    asm("v_cvt_pk_bf16_f32 %0, %1, %2" : "=v"(r) : "v"(x), "v"(y));
    return r;
}

// v_permlane32_swap_b32 (validated r1):
//   a' = [a.lanes0-31 | b.lanes0-31], b' = [a.lanes32-63 | b.lanes32-63]
__device__ __forceinline__ void plswap(unsigned& a, unsigned& b) {
    asm("v_permlane32_swap_b32 %0, %1" : "+v"(a), "+v"(b));
}

// v_permlane16_swap_b32: a.g1 <-> b.g0, a.g3 <-> b.g2  (g = 16-lane group)
__device__ __forceinline__ void pl16swap(unsigned& a, unsigned& b) {
    asm("v_permlane16_swap_b32 %0, %1" : "+v"(a), "+v"(b));
}

__device__ __forceinline__ float fexp2(float x) {
#if __has_builtin(__builtin_amdgcn_exp2f)
    return __builtin_amdgcn_exp2f(x);
#else
    return exp2f(x);
#endif
}

__device__ __forceinline__ bf16x8 ld_frag(const us16* p) {
    u32x4 u = *reinterpret_cast<const u32x4*>(p);
    return __builtin_bit_cast(bf16x8, u);
}

// load 8 consecutive fp32 and RNE-convert to a bf16x8 fragment
__device__ __forceinline__ bf16x8 cvt_frag(const float* p) {
    f32x4 a = *reinterpret_cast<const f32x4*>(p);
    f32x4 b = *reinterpret_cast<const f32x4*>(p + 4);
    u32x4 o;
    o[0] = f2bf_u(a[0]) | (f2bf_u(a[1]) << 16);
    o[1] = f2bf_u(a[2]) | (f2bf_u(a[3]) << 16);
    o[2] = f2bf_u(b[0]) | (f2bf_u(b[1]) << 16);
    o[3] = f2bf_u(b[2]) | (f2bf_u(b[3]) << 16);
    return __builtin_bit_cast(bf16x8, o);
}

// ------------------------------------------------------------- QKV projection
// 384 blocks: z = blockIdx>>7 (0:Q 1:K 2:V), tile = blockIdx&127 (64 rows).
// Reads x and W in fp32, converts inline. Q pre-scaled by SCALE_L2E.
// Also zeroes the 32 per-qtile completion counters (kernel-boundary coherence
// makes them visible to attn).
__global__ __launch_bounds__(256) void proj_qkv(
    const float* __restrict__ x,
    const float* __restrict__ wq, const float* __restrict__ bq,
    const float* __restrict__ wk, const float* __restrict__ bk,
    const float* __restrict__ wv, const float* __restrict__ bv,
    us16* __restrict__ Qb, us16* __restrict__ Kb, us16* __restrict__ Vt,
    int* __restrict__ cnt)
{
    __shared__ us16 ldsT[4][16 * 136];   // per-wave transpose tile (Q/K path)

    if (blockIdx.x == 0 && threadIdx.x < 32) cnt[threadIdx.x] = 0;

    int z = blockIdx.x >> 7;
    int tile = blockIdx.x & 127;
    const float* W = z == 0 ? wq : z == 1 ? wk : wv;
    const float* bias = z == 0 ? bq : z == 1 ? bk : bv;
    float osc = z == 0 ? SCALE_L2E : 1.0f;

    int w = threadIdx.x >> 6, lane = threadIdx.x & 63;
    int quad = lane >> 4, l15 = lane & 15;
    int rbase = tile * 64 + w * 16;

    bf16x8 af[4];
#pragma unroll
    for (int ks = 0; ks < 4; ++ks)
        af[ks] = cvt_frag(x + (rbase + l15) * 128 + ks * 32 + quad * 8);

    f32x4 acc[8];
#pragma unroll
    for (int nt = 0; nt < 8; ++nt) acc[nt] = f32x4{0.f, 0.f, 0.f, 0.f};

#pragma unroll
    for (int nt = 0; nt < 8; ++nt) {
#pragma unroll
        for (int ks = 0; ks < 4; ++ks) {
            bf16x8 bf = cvt_frag(W + (nt * 16 + l15) * 128 + ks * 32 + quad * 8);
            acc[nt] = __builtin_amdgcn_mfma_f32_16x16x32_bf16(af[ks], bf, acc[nt], 0, 0, 0);
        }
    }

    if (z < 2) {
        // row-major out: transpose through per-wave LDS tile, store 16B chunks
        us16* T = &ldsT[w][0];
        us16* Out = z == 0 ? Qb : Kb;
#pragma unroll
        for (int nt = 0; nt < 8; ++nt) {
            float bb = bias[nt * 16 + l15];
#pragma unroll
            for (int r = 0; r < 4; ++r)
                T[(quad * 4 + r) * 136 + nt * 16 + l15] =
                    (us16)f2bf_u((acc[nt][r] + bb) * osc);
        }
        // wave-private tile: drain LDS writes before readback (no barrier)
        asm volatile("s_waitcnt lgkmcnt(0)" ::: "memory");
        __builtin_amdgcn_sched_barrier(0);
        int row = lane >> 2, seg = lane & 3;   // 4 lanes per row, 64B each
        const us16* src = T + row * 136 + seg * 32;
        us16* dst = Out + (rbase + row) * 128 + seg * 32;
#pragma unroll
        for (int c = 0; c < 4; ++c)
            *reinterpret_cast<u32x4*>(dst + c * 8) =
                *reinterpret_cast<const u32x4*>(src + c * 8);
    } else {
        // V^T out: columns rbase+quad*4..+4 of rows d = nt*16+l15 (8B packed)
#pragma unroll
        for (int nt = 0; nt < 8; ++nt) {
            float bb = bias[nt * 16 + l15];
            int d = nt * 16 + l15, r0 = rbase + quad * 4;
            u32x2 pk;
            pk[0] = f2bf_u(acc[nt][0] + bb) | (f2bf_u(acc[nt][1] + bb) << 16);
            pk[1] = f2bf_u(acc[nt][2] + bb) | (f2bf_u(acc[nt][3] + bb) << 16);
            *reinterpret_cast<u32x2*>(Vt + d * NTOK + r0) = pk;
        }
    }
}

// ---------------------------------------------- flash attention + combine
// 256 WGs = 32 q-tiles (256 rows) x 8 KV chunks; 512 threads (8 waves), 1
// WG/CU. Wave owns 32 Q rows. r7 attn body; last-finishing chunk-WG per
// q-tile performs combine + output projection for its 256 rows.
__global__ __launch_bounds__(512, 2) void attn_combine(
    const us16* __restrict__ Qb, const us16* __restrict__ Kb,
    const us16* __restrict__ Vt,
    float* __restrict__ Opart, float* __restrict__ Lpart,
    int* __restrict__ cnt,
    const float* __restrict__ Wo, const float* __restrict__ bo,
    float* __restrict__ out)
{
    __shared__ us16 smem[2 * KTILE + 2 * VTILE];   // 71680 B, reused by combine
    __shared__ int shDo;

    int bid = blockIdx.x;
    int qtile = bid >> 3, chunk = bid & 7;
    int tid = threadIdx.x, w = tid >> 6, lane = tid & 63;
    int quad = lane >> 4, l15 = lane & 15;
    int qb0 = qtile * 256 + w * 32;
    int k0 = chunk * 1024;

    us16* ldsK0 = smem;                 // [2][64*136]
    us16* ldsV0 = smem + 2 * KTILE;     // [2][128*72]

    bf16x8 qf[2][4];
#pragma unroll
    for (int mt = 0; mt < 2; ++mt)
#pragma unroll
        for (int ks = 0; ks < 4; ++ks)
            qf[mt][ks] = ld_frag(Qb + (qb0 + mt * 16 + l15) * 128 + ks * 32 + quad * 8);

    f32x4 o[2][8];
#pragma unroll
    for (int mt = 0; mt < 2; ++mt)
#pragma unroll
        for (int dt = 0; dt < 8; ++dt) o[mt][dt] = f32x4{0.f, 0.f, 0.f, 0.f};

    f32x4 lacc[2];
    lacc[0] = f32x4{0.f, 0.f, 0.f, 0.f};
    lacc[1] = f32x4{0.f, 0.f, 0.f, 0.f};

    u32x4 onesu;
    onesu[0] = onesu[1] = onesu[2] = onesu[3] = 0x3F803F80u;  // bf16 1.0 x8
    bf16x8 ones = __builtin_bit_cast(bf16x8, onesu);

    // ---- prologue: stage tile 0 into buffer 0 (512 thr x 16B x 2 passes/tile)
#pragma unroll
    for (int c = 0; c < 2; ++c) {
        int idx = tid + c * 512, r = idx >> 4, cc = idx & 15;
        *reinterpret_cast<u32x4*>(ldsK0 + r * 136 + cc * 8) =
            *reinterpret_cast<const u32x4*>(Kb + (k0 + r) * 128 + cc * 8);
    }
#pragma unroll
    for (int c = 0; c < 2; ++c) {
        int idx = tid + c * 512, r = idx >> 3, cc = idx & 7;
        *reinterpret_cast<u32x4*>(ldsV0 + r * 72 + cc * 8) =
            *reinterpret_cast<const u32x4*>(Vt + (size_t)r * NTOK + k0 + cc * 8);
    }
    __syncthreads();

    for (int it = 0; it < 16; ++it) {
        int cur = it & 1;
        const us16* K_ = ldsK0 + cur * KTILE;
        const us16* V_ = ldsV0 + cur * VTILE;

        // ---- issue next tile's global loads (fenced at iter top)
        u32x4 kreg[2], vreg[2];
        if (it < 15) {
            int kk = k0 + (it + 1) * 64;
#pragma unroll
            for (int c = 0; c < 2; ++c) {
                int idx = tid + c * 512, r = idx >> 4, cc = idx & 15;
                kreg[c] = *reinterpret_cast<const u32x4*>(Kb + (kk + r) * 128 + cc * 8);
            }
#pragma unroll
            for (int c = 0; c < 2; ++c) {
                int idx = tid + c * 512, r = idx >> 3, cc = idx & 7;
                vreg[c] = *reinterpret_cast<const u32x4*>(Vt + (size_t)r * NTOK + kk + cc * 8);
            }
            __builtin_amdgcn_sched_barrier(0);
        }

        // ---- S^T = K Q^T: lane (quad,l15) reg r = S[m=l15][n=nt*16+quad*4+r]
        f32x4 s[2][4];
#pragma unroll
        for (int mt = 0; mt < 2; ++mt)
#pragma unroll
            for (int nt = 0; nt < 4; ++nt) s[mt][nt] = f32x4{0.f, 0.f, 0.f, 0.f};

        __builtin_amdgcn_s_setprio(1);
#pragma unroll
        for (int nt = 0; nt < 4; ++nt) {
#pragma unroll
            for (int ks = 0; ks < 4; ++ks) {
                bf16x8 kf = ld_frag(K_ + (nt * 16 + l15) * 136 + ks * 32 + quad * 8);
                s[0][nt] = __builtin_amdgcn_mfma_f32_16x16x32_bf16(kf, qf[0][ks], s[0][nt], 0, 0, 0);
                s[1][nt] = __builtin_amdgcn_mfma_f32_16x16x32_bf16(kf, qf[1][ks], s[1][nt], 0, 0, 0);
            }
        }
        __builtin_amdgcn_s_setprio(0);

        // ---- P = exp2(S^T); cvt_pk pairs; permlane reshape -> PV A-frags
        bf16x8 afP[2][2];
#pragma unroll
        for (int mt = 0; mt < 2; ++mt) {
            unsigned W[4][2];
#pragma unroll
            for (int nt = 0; nt < 4; ++nt) {
                float p0 = fexp2(s[mt][nt][0]);
                float p1 = fexp2(s[mt][nt][1]);
                float p2 = fexp2(s[mt][nt][2]);
                float p3 = fexp2(s[mt][nt][3]);
                W[nt][0] = cvtpk_bf16(p0, p1);
                W[nt][1] = cvtpk_bf16(p2, p3);
            }
#pragma unroll
            for (int k2 = 0; k2 < 2; ++k2) {
                u32x4 f;
                {
                    unsigned X = W[2 * k2][0], Y = W[2 * k2 + 1][0];
                    plswap(X, Y); pl16swap(X, Y);
                    f[0] = X; f[2] = Y;
                }
                {
                    unsigned X = W[2 * k2][1], Y = W[2 * k2 + 1][1];
                    plswap(X, Y); pl16swap(X, Y);
                    f[1] = X; f[3] = Y;
                }
                afP[mt][k2] = __builtin_bit_cast(bf16x8, f);
            }
        }

        // ---- l += P @ ones;  O += P V
        lacc[0] = __builtin_amdgcn_mfma_f32_16x16x32_bf16(afP[0][0], ones, lacc[0], 0, 0, 0);
        lacc[0] = __builtin_amdgcn_mfma_f32_16x16x32_bf16(afP[0][1], ones, lacc[0], 0, 0, 0);
        lacc[1] = __builtin_amdgcn_mfma_f32_16x16x32_bf16(afP[1][0], ones, lacc[1], 0, 0, 0);
        lacc[1] = __builtin_amdgcn_mfma_f32_16x16x32_bf16(afP[1][1], ones, lacc[1], 0, 0, 0);

        __builtin_amdgcn_s_setprio(1);
#pragma unroll
        for (int dt = 0; dt < 8; ++dt) {
#pragma unroll
            for (int k2 = 0; k2 < 2; ++k2) {
                bf16x8 bv = ld_frag(V_ + (dt * 16 + l15) * 72 + k2 * 32 + quad * 8);
                o[0][dt] = __builtin_amdgcn_mfma_f32_16x16x32_bf16(afP[0][k2], bv, o[0][dt], 0, 0, 0);
                o[1][dt] = __builtin_amdgcn_mfma_f32_16x16x32_bf16(afP[1][k2], bv, o[1][dt], 0, 0, 0);
            }
        }
        __builtin_amdgcn_s_setprio(0);

        // ---- write prefetched tile into the other buffer, then ONE barrier
        if (it < 15) {
            __builtin_amdgcn_sched_barrier(0);
            us16* Kn = ldsK0 + (cur ^ 1) * KTILE;
            us16* Vn = ldsV0 + (cur ^ 1) * VTILE;
#pragma unroll
            for (int c = 0; c < 2; ++c) {
                int idx = tid + c * 512, r = idx >> 4, cc = idx & 15;
                *reinterpret_cast<u32x4*>(Kn + r * 136 + cc * 8) = kreg[c];
            }
#pragma unroll
            for (int c = 0; c < 2; ++c) {
                int idx = tid + c * 512, r = idx >> 3, cc = idx & 7;
                *reinterpret_cast<u32x4*>(Vn + r * 72 + cc * 8) = vreg[c];
            }
        }
        __syncthreads();
    }

    // ---- write unnormalized partials (O rows: qb0+mt*16+quad*4+r, cols dt*16+l15)
#pragma unroll
    for (int mt = 0; mt < 2; ++mt)
#pragma unroll
        for (int dt = 0; dt < 8; ++dt)
#pragma unroll
            for (int r = 0; r < 4; ++r) {
                int row = qb0 + mt * 16 + quad * 4 + r;
                Opart[(size_t)(chunk * NTOK + row) * 128 + dt * 16 + l15] = o[mt][dt][r];
            }
    if (l15 == 0) {
#pragma unroll
        for (int mt = 0; mt < 2; ++mt)
#pragma unroll
            for (int r = 0; r < 4; ++r) {
                int row = qb0 + mt * 16 + quad * 4 + r;
                Lpart[chunk * NTOK + row] = lacc[mt][r];
            }
    }

    // ---- completion handshake: last chunk-WG of this q-tile combines
    __threadfence();                       // release our partials device-wide
    if (tid == 0) shDo = (atomicAdd(&cnt[qtile], 1) == CHUNKS - 1) ? 1 : 0;
    __syncthreads();
    if (!shDo) return;
    __threadfence();                       // acquire the other 7 WGs' writes

    // ==================== combine + output projection (256 rows) ============
    {
        us16* ldsO = smem;                               // 256 x 136 bf16
        float* ldsLf = (float*)(smem + 256 * 136);       // 256 fp32 (fits)
        int r0row = qtile * 256;

        if (tid < 256) {
            float L = 0.f;
#pragma unroll
            for (int c = 0; c < CHUNKS; ++c) L += Lpart[c * NTOK + r0row + tid];
            ldsLf[tid] = 1.0f / L;
        }

        // sum 8 chunk partials: 256x128 fp32, thread covers 16x f32x4
        f32x4 acc[16];
#pragma unroll
        for (int j = 0; j < 16; ++j) acc[j] = f32x4{0.f, 0.f, 0.f, 0.f};

#pragma unroll
        for (int c = 0; c < CHUNKS; ++c) {
            const float* src = Opart + (size_t)(c * NTOK + r0row) * 128;
#pragma unroll
            for (int j = 0; j < 16; ++j) {
                f32x4 v = *reinterpret_cast<const f32x4*>(src + j * 2048 + tid * 4);
                acc[j] += v;
            }
        }
        __syncthreads();   // ldsLf ready; attn-phase LDS reads long done

#pragma unroll
        for (int j = 0; j < 16; ++j) {
            int flat = j * 2048 + tid * 4;
            int row = flat >> 7, col = flat & 127;
            float sc = ldsLf[row];
            u32x2 wv;
            wv[0] = pk_bf16(acc[j][0] * sc, acc[j][1] * sc);
            wv[1] = pk_bf16(acc[j][2] * sc, acc[j][3] * sc);
            *reinterpret_cast<u32x2*>(ldsO + row * 136 + col) = wv;
        }
        __syncthreads();

        // GEMM: wave w -> rows [w*32, +32), all 128 cols (4 col-tiles of 32)
        int l31 = lane & 31, hi = lane >> 5;

        bf16x8 af[8];
#pragma unroll
        for (int ks = 0; ks < 8; ++ks)
            af[ks] = ld_frag(ldsO + (w * 32 + l31) * 136 + ks * 16 + hi * 8);

#pragma unroll
        for (int ct = 0; ct < 4; ++ct) {
            f32x16 acc2;
#pragma unroll
            for (int r = 0; r < 16; ++r) acc2[r] = 0.f;

#pragma unroll
            for (int ks = 0; ks < 8; ++ks) {
                bf16x8 bfw = cvt_frag(Wo + (ct * 32 + l31) * 128 + ks * 16 + hi * 8);
                acc2 = __builtin_amdgcn_mfma_f32_32x32x16_bf16(af[ks], bfw, acc2, 0, 0, 0);
            }

            float bb = bo[ct * 32 + l31];
#pragma unroll
            for (int r = 0; r < 16; ++r) {
                int m = (r & 3) + 8 * (r >> 2) + 4 * hi;
                out[(size_t)(r0row + w * 32 + m) * 128 + ct * 32 + l31] = acc2[r] + bb;
            }
        }
    }
}

// ------------------------------------------------------------------- launcher
extern "C" void kernel_launch(void* const* d_in, const int* in_sizes, int n_in,
                              void* d_out, int out_size, void* d_ws, size_t ws_size,
                              hipStream_t stream)
{
    const float* x  = (const float*)d_in[0];
    const float* Wq = (const float*)d_in[1];
    const float* bq = (const float*)d_in[2];
    const float* Wk = (const float*)d_in[3];
    const float* bk = (const float*)d_in[4];
    const float* Wv = (const float*)d_in[5];
    const float* bv = (const float*)d_in[6];
    const float* Wo = (const float*)d_in[7];
    const float* bo = (const float*)d_in[8];

    char* ws = (char*)d_ws;
    const size_t MB = 1024 * 1024;
    us16* Qb  = (us16*)(ws + 0 * MB);                   // 2 MB
    us16* Kb  = (us16*)(ws + 2 * MB);                   // 2 MB
    us16* Vt  = (us16*)(ws + 4 * MB);                   // 2 MB
    float* Lp = (float*)(ws + 6 * MB);                  // 256 KB
    int*   cnt = (int*)(ws + 6 * MB + 256 * 1024);      // 128 B
    float* Op = (float*)(ws + 7 * MB);                  // 32 MB
    // total ws use: 39 MB

    proj_qkv<<<384, 256, 0, stream>>>(x, Wq, bq, Wk, bk, Wv, bv, Qb, Kb, Vt, cnt);
    attn_combine<<<256, 512, 0, stream>>>(Qb, Kb, Vt, Op, Lp, cnt, Wo, bo,
                                          (float*)d_out);
}

// Round 11
// 138.043 us; speedup vs baseline: 2.5049x; 1.6772x over previous
//
#include <hip/hip_runtime.h>
#include <math.h>

// ----------------------------------------------------------------------------
// SingleHeadSelfAttention, N=8192, DIM=128, fp32 in/out.
// THREE kernels (r9/r10 lesson, measured twice: grid.sync ~100us and
// device-scope threadfence+atomic handshake ~+120us -- kernel-boundary
// coherence is the only cheap cross-XCD sync on MI355X):
//   1. proj_qkv:     reads x, Wq/Wk/Wv fp32 directly (inline RNE bf16 cvt).
//                    Q pre-scaled by scale*log2e; K row-major; V^T [128x8192].
//   2. attn:         flash attention, no running max (scores bounded).
//                    16x16 structure, P LDS-free (cvt_pk + permlane32/16,
//                    r5), K/V double-buffered reg-prefetch staging (r6),
//                    8-wave 1-WG/CU (r7). NEW (r11): BK=128 keys per staged
//                    tile -- same 64-key compute body run twice per tile,
//                    barriers 16 -> 8, staging drains halved, 2x longer MFMA
//                    runs between barriers. LDS 136 KB (1 WG/CU, as before).
//   3. combine_proj: 256 blocks x 32 rows: sum 8 chunk partials, normalize,
//                    bf16 -> LDS, 32x32x16 GEMM @ Wo^T (inline cvt) + bo.
// ----------------------------------------------------------------------------

typedef __bf16 bf16x8 __attribute__((ext_vector_type(8)));
typedef float f32x4 __attribute__((ext_vector_type(4)));
typedef float f32x16 __attribute__((ext_vector_type(16)));
typedef unsigned int u32x4 __attribute__((ext_vector_type(4)));
typedef unsigned int u32x2 __attribute__((ext_vector_type(2)));
typedef unsigned short us16;

#define NTOK 8192
#define CHUNKS 8
#define KT2 (128 * 136)   // K tile elems: 128 rows x pitch 136
#define VT2 (128 * 136)   // V^T tile elems: 128 d-rows x pitch 136 (128 keys)

// scale * log2(e);  scale = 1/sqrt(128)
static constexpr float SCALE_L2E = 0.08838834764831845f * 1.4426950408889634f;

__device__ __forceinline__ unsigned f2bf_u(float x) {
    unsigned u = __builtin_bit_cast(unsigned, x);
    return (u + 0x7FFFu + ((u >> 16) & 1u)) >> 16;   // RNE, no NaN inputs here
}

__device__ __forceinline__ unsigned pk_bf16(float x, float y) {
    unsigned a = __builtin_bit_cast(unsigned, x) + 0x8000u;
    unsigned b = __builtin_bit_cast(unsigned, y) + 0x8000u;
#if __has_builtin(__builtin_amdgcn_perm)
    return __builtin_amdgcn_perm(b, a, 0x07060302u);  // {b.hi16 : a.hi16}
#else
    return (a >> 16) | (b & 0xFFFF0000u);
#endif
}

// single-instruction RNE pack of two fp32 -> bf16x2 (low = x, high = y)
__device__ __forceinline__ unsigned cvtpk_bf16(float x, float y) {
    unsigned r;
    asm("v_cvt_pk_bf16_f32 %0, %1, %2" : "=v"(r) : "v"(x), "v"(y));
    return r;
}

// v_permlane32_swap_b32 (validated r1):
//   a' = [a.lanes0-31 | b.lanes0-31], b' = [a.lanes32-63 | b.lanes32-63]
__device__ __forceinline__ void plswap(unsigned& a, unsigned& b) {
    asm("v_permlane32_swap_b32 %0, %1" : "+v"(a), "+v"(b));
}

// v_permlane16_swap_b32: a.g1 <-> b.g0, a.g3 <-> b.g2  (g = 16-lane group)
__device__ __forceinline__ void pl16swap(unsigned& a, unsigned& b) {
    asm("v_permlane16_swap_b32 %0, %1" : "+v"(a), "+v"(b));
}

__device__ __forceinline__ float fexp2(float x) {
#if __has_builtin(__builtin_amdgcn_exp2f)
    return __builtin_amdgcn_exp2f(x);
#else
    return exp2f(x);
#endif
}

__device__ __forceinline__ bf16x8 ld_frag(const us16* p) {
    u32x4 u = *reinterpret_cast<const u32x4*>(p);
    return __builtin_bit_cast(bf16x8, u);
}

// load 8 consecutive fp32 and RNE-convert to a bf16x8 fragment
__device__ __forceinline__ bf16x8 cvt_frag(const float* p) {
    f32x4 a = *reinterpret_cast<const f32x4*>(p);
    f32x4 b = *reinterpret_cast<const f32x4*>(p + 4);
    u32x4 o;
    o[0] = f2bf_u(a[0]) | (f2bf_u(a[1]) << 16);
    o[1] = f2bf_u(a[2]) | (f2bf_u(a[3]) << 16);
    o[2] = f2bf_u(b[0]) | (f2bf_u(b[1]) << 16);
    o[3] = f2bf_u(b[2]) | (f2bf_u(b[3]) << 16);
    return __builtin_bit_cast(bf16x8, o);
}

// ------------------------------------------------------------- QKV projection
// 384 blocks: z = blockIdx>>7 (0:Q 1:K 2:V), tile = blockIdx&127 (64 rows).
// Reads x and W in fp32, converts inline. Q pre-scaled by SCALE_L2E.
__global__ __launch_bounds__(256) void proj_qkv(
    const float* __restrict__ x,
    const float* __restrict__ wq, const float* __restrict__ bq,
    const float* __restrict__ wk, const float* __restrict__ bk,
    const float* __restrict__ wv, const float* __restrict__ bv,
    us16* __restrict__ Qb, us16* __restrict__ Kb, us16* __restrict__ Vt)
{
    __shared__ us16 ldsT[4][16 * 136];   // per-wave transpose tile (Q/K path)

    int z = blockIdx.x >> 7;
    int tile = blockIdx.x & 127;
    const float* W = z == 0 ? wq : z == 1 ? wk : wv;
    const float* bias = z == 0 ? bq : z == 1 ? bk : bv;
    float osc = z == 0 ? SCALE_L2E : 1.0f;

    int w = threadIdx.x >> 6, lane = threadIdx.x & 63;
    int quad = lane >> 4, l15 = lane & 15;
    int rbase = tile * 64 + w * 16;

    bf16x8 af[4];
#pragma unroll
    for (int ks = 0; ks < 4; ++ks)
        af[ks] = cvt_frag(x + (rbase + l15) * 128 + ks * 32 + quad * 8);

    f32x4 acc[8];
#pragma unroll
    for (int nt = 0; nt < 8; ++nt) acc[nt] = f32x4{0.f, 0.f, 0.f, 0.f};

#pragma unroll
    for (int nt = 0; nt < 8; ++nt) {
#pragma unroll
        for (int ks = 0; ks < 4; ++ks) {
            bf16x8 bf = cvt_frag(W + (nt * 16 + l15) * 128 + ks * 32 + quad * 8);
            acc[nt] = __builtin_amdgcn_mfma_f32_16x16x32_bf16(af[ks], bf, acc[nt], 0, 0, 0);
        }
    }

    if (z < 2) {
        // row-major out: transpose through per-wave LDS tile, store 16B chunks
        us16* T = &ldsT[w][0];
        us16* Out = z == 0 ? Qb : Kb;
#pragma unroll
        for (int nt = 0; nt < 8; ++nt) {
            float bb = bias[nt * 16 + l15];
#pragma unroll
            for (int r = 0; r < 4; ++r)
                T[(quad * 4 + r) * 136 + nt * 16 + l15] =
                    (us16)f2bf_u((acc[nt][r] + bb) * osc);
        }
        // wave-private tile: drain LDS writes before readback (no barrier)
        asm volatile("s_waitcnt lgkmcnt(0)" ::: "memory");
        __builtin_amdgcn_sched_barrier(0);
        int row = lane >> 2, seg = lane & 3;   // 4 lanes per row, 64B each
        const us16* src = T + row * 136 + seg * 32;
        us16* dst = Out + (rbase + row) * 128 + seg * 32;
#pragma unroll
        for (int c = 0; c < 4; ++c)
            *reinterpret_cast<u32x4*>(dst + c * 8) =
                *reinterpret_cast<const u32x4*>(src + c * 8);
    } else {
        // V^T out: columns rbase+quad*4..+4 of rows d = nt*16+l15 (8B packed)
#pragma unroll
        for (int nt = 0; nt < 8; ++nt) {
            float bb = bias[nt * 16 + l15];
            int d = nt * 16 + l15, r0 = rbase + quad * 4;
            u32x2 pk;
            pk[0] = f2bf_u(acc[nt][0] + bb) | (f2bf_u(acc[nt][1] + bb) << 16);
            pk[1] = f2bf_u(acc[nt][2] + bb) | (f2bf_u(acc[nt][3] + bb) << 16);
            *reinterpret_cast<u32x2*>(Vt + d * NTOK + r0) = pk;
        }
    }
}

// ------------------------------------------------------------ flash attention
// 256 WGs = 32 q-tiles (256 rows) x 8 KV chunks; 512 threads (8 waves), 1
// WG/CU. Wave owns 32 Q rows. BK=128 keys per staged tile, 8 iterations;
// the proven 64-key compute body runs twice per tile (half = 0,1).
// P LDS-free (cvt_pk + permlane32/16_swap). K/V double-buffered: next-tile
// global loads at iter top (fenced), ds_write after compute, one barrier/iter.
__global__ __launch_bounds__(512, 1) void attn(
    const us16* __restrict__ Qb, const us16* __restrict__ Kb,
    const us16* __restrict__ Vt,
    float* __restrict__ Opart, float* __restrict__ Lpart)
{
    __shared__ us16 smem[2 * KT2 + 2 * VT2];   // 139264 B (1 WG/CU)

    int bid = blockIdx.x;
    int qtile = bid >> 3, chunk = bid & 7;
    int tid = threadIdx.x, w = tid >> 6, lane = tid & 63;
    int quad = lane >> 4, l15 = lane & 15;
    int qb0 = qtile * 256 + w * 32;
    int k0 = chunk * 1024;

    us16* ldsK0 = smem;                 // [2][128*136]
    us16* ldsV0 = smem + 2 * KT2;       // [2][128*136]

    bf16x8 qf[2][4];
#pragma unroll
    for (int mt = 0; mt < 2; ++mt)
#pragma unroll
        for (int ks = 0; ks < 4; ++ks)
            qf[mt][ks] = ld_frag(Qb + (qb0 + mt * 16 + l15) * 128 + ks * 32 + quad * 8);

    f32x4 o[2][8];
#pragma unroll
    for (int mt = 0; mt < 2; ++mt)
#pragma unroll
        for (int dt = 0; dt < 8; ++dt) o[mt][dt] = f32x4{0.f, 0.f, 0.f, 0.f};

    f32x4 lacc[2];
    lacc[0] = f32x4{0.f, 0.f, 0.f, 0.f};
    lacc[1] = f32x4{0.f, 0.f, 0.f, 0.f};

    u32x4 onesu;
    onesu[0] = onesu[1] = onesu[2] = onesu[3] = 0x3F803F80u;  // bf16 1.0 x8
    bf16x8 ones = __builtin_bit_cast(bf16x8, onesu);

    // ---- prologue: stage tile 0 (128x128 K and 128x128 V^T, 4 passes each)
#pragma unroll
    for (int c = 0; c < 4; ++c) {
        int idx = tid + c * 512, r = idx >> 4, cc = idx & 15;
        *reinterpret_cast<u32x4*>(ldsK0 + r * 136 + cc * 8) =
            *reinterpret_cast<const u32x4*>(Kb + (k0 + r) * 128 + cc * 8);
    }
#pragma unroll
    for (int c = 0; c < 4; ++c) {
        int idx = tid + c * 512, r = idx >> 4, cc = idx & 15;
        *reinterpret_cast<u32x4*>(ldsV0 + r * 136 + cc * 8) =
            *reinterpret_cast<const u32x4*>(Vt + (size_t)r * NTOK + k0 + cc * 8);
    }
    __syncthreads();

    for (int it = 0; it < 8; ++it) {
        int cur = it & 1;
        const us16* K_ = ldsK0 + cur * KT2;
        const us16* V_ = ldsV0 + cur * VT2;

        // ---- issue next tile's global loads (fenced at iter top)
        u32x4 kreg[4], vreg[4];
        if (it < 7) {
            int kk = k0 + (it + 1) * 128;
#pragma unroll
            for (int c = 0; c < 4; ++c) {
                int idx = tid + c * 512, r = idx >> 4, cc = idx & 15;
                kreg[c] = *reinterpret_cast<const u32x4*>(Kb + (kk + r) * 128 + cc * 8);
            }
#pragma unroll
            for (int c = 0; c < 4; ++c) {
                int idx = tid + c * 512, r = idx >> 4, cc = idx & 15;
                vreg[c] = *reinterpret_cast<const u32x4*>(Vt + (size_t)r * NTOK + kk + cc * 8);
            }
            __builtin_amdgcn_sched_barrier(0);
        }

#pragma unroll
        for (int half = 0; half < 2; ++half) {
            int kb = half * 64;

            // ---- S^T = K Q^T: lane (quad,l15) reg r = S[m=l15][n=kb+nt*16+quad*4+r]
            f32x4 s[2][4];
#pragma unroll
            for (int mt = 0; mt < 2; ++mt)
#pragma unroll
                for (int nt = 0; nt < 4; ++nt) s[mt][nt] = f32x4{0.f, 0.f, 0.f, 0.f};

            __builtin_amdgcn_s_setprio(1);
#pragma unroll
            for (int nt = 0; nt < 4; ++nt) {
#pragma unroll
                for (int ks = 0; ks < 4; ++ks) {
                    bf16x8 kf = ld_frag(K_ + (kb + nt * 16 + l15) * 136 + ks * 32 + quad * 8);
                    s[0][nt] = __builtin_amdgcn_mfma_f32_16x16x32_bf16(kf, qf[0][ks], s[0][nt], 0, 0, 0);
                    s[1][nt] = __builtin_amdgcn_mfma_f32_16x16x32_bf16(kf, qf[1][ks], s[1][nt], 0, 0, 0);
                }
            }
            __builtin_amdgcn_s_setprio(0);

            // ---- P = exp2(S^T); cvt_pk pairs; permlane reshape -> PV A-frags
            bf16x8 afP[2][2];
#pragma unroll
            for (int mt = 0; mt < 2; ++mt) {
                unsigned W[4][2];
#pragma unroll
                for (int nt = 0; nt < 4; ++nt) {
                    float p0 = fexp2(s[mt][nt][0]);
                    float p1 = fexp2(s[mt][nt][1]);
                    float p2 = fexp2(s[mt][nt][2]);
                    float p3 = fexp2(s[mt][nt][3]);
                    W[nt][0] = cvtpk_bf16(p0, p1);
                    W[nt][1] = cvtpk_bf16(p2, p3);
                }
#pragma unroll
                for (int k2 = 0; k2 < 2; ++k2) {
                    u32x4 f;
                    {
                        unsigned X = W[2 * k2][0], Y = W[2 * k2 + 1][0];
                        plswap(X, Y); pl16swap(X, Y);
                        f[0] = X; f[2] = Y;
                    }
                    {
                        unsigned X = W[2 * k2][1], Y = W[2 * k2 + 1][1];
                        plswap(X, Y); pl16swap(X, Y);
                        f[1] = X; f[3] = Y;
                    }
                    afP[mt][k2] = __builtin_bit_cast(bf16x8, f);
                }
            }

            // ---- l += P @ ones;  O += P V
            lacc[0] = __builtin_amdgcn_mfma_f32_16x16x32_bf16(afP[0][0], ones, lacc[0], 0, 0, 0);
            lacc[0] = __builtin_amdgcn_mfma_f32_16x16x32_bf16(afP[0][1], ones, lacc[0], 0, 0, 0);
            lacc[1] = __builtin_amdgcn_mfma_f32_16x16x32_bf16(afP[1][0], ones, lacc[1], 0, 0, 0);
            lacc[1] = __builtin_amdgcn_mfma_f32_16x16x32_bf16(afP[1][1], ones, lacc[1], 0, 0, 0);

            __builtin_amdgcn_s_setprio(1);
#pragma unroll
            for (int dt = 0; dt < 8; ++dt) {
#pragma unroll
                for (int k2 = 0; k2 < 2; ++k2) {
                    bf16x8 bv = ld_frag(V_ + (dt * 16 + l15) * 136 + kb + k2 * 32 + quad * 8);
                    o[0][dt] = __builtin_amdgcn_mfma_f32_16x16x32_bf16(afP[0][k2], bv, o[0][dt], 0, 0, 0);
                    o[1][dt] = __builtin_amdgcn_mfma_f32_16x16x32_bf16(afP[1][k2], bv, o[1][dt], 0, 0, 0);
                }
            }
            __builtin_amdgcn_s_setprio(0);
        }

        // ---- write prefetched tile into the other buffer, then ONE barrier
        if (it < 7) {
            __builtin_amdgcn_sched_barrier(0);
            us16* Kn = ldsK0 + (cur ^ 1) * KT2;
            us16* Vn = ldsV0 + (cur ^ 1) * VT2;
#pragma unroll
            for (int c = 0; c < 4; ++c) {
                int idx = tid + c * 512, r = idx >> 4, cc = idx & 15;
                *reinterpret_cast<u32x4*>(Kn + r * 136 + cc * 8) = kreg[c];
            }
#pragma unroll
            for (int c = 0; c < 4; ++c) {
                int idx = tid + c * 512, r = idx >> 4, cc = idx & 15;
                *reinterpret_cast<u32x4*>(Vn + r * 136 + cc * 8) = vreg[c];
            }
        }
        __syncthreads();
    }

    // ---- write unnormalized partials (O rows: qb0+mt*16+quad*4+r, cols dt*16+l15)
#pragma unroll
    for (int mt = 0; mt < 2; ++mt)
#pragma unroll
        for (int dt = 0; dt < 8; ++dt)
#pragma unroll
            for (int r = 0; r < 4; ++r) {
                int row = qb0 + mt * 16 + quad * 4 + r;
                Opart[(size_t)(chunk * NTOK + row) * 128 + dt * 16 + l15] = o[mt][dt][r];
            }
    if (l15 == 0) {
#pragma unroll
        for (int mt = 0; mt < 2; ++mt)
#pragma unroll
            for (int r = 0; r < 4; ++r) {
                int row = qb0 + mt * 16 + quad * 4 + r;
                Lpart[chunk * NTOK + row] = lacc[mt][r];
            }
    }
}

// ------------------------------------- combine partials + output projection
// 256 blocks x 256 threads; block handles 32 rows: sum 8 chunk partials,
// normalize by sum(l), bf16 -> LDS, 32x32x16 GEMM @ Wo^T (inline cvt) + bo.
__global__ __launch_bounds__(256) void combine_proj(
    const float* __restrict__ Opart, const float* __restrict__ Lpart,
    const float* __restrict__ Wo, const float* __restrict__ bo,
    float* __restrict__ out)
{
    __shared__ us16 ldsO[32 * 136];
    __shared__ float ldsL[32];

    int tile = blockIdx.x, t = threadIdx.x;
    int r0 = tile * 32;

    if (t < 32) {
        float L = 0.f;
#pragma unroll
        for (int c = 0; c < CHUNKS; ++c) L += Lpart[c * NTOK + r0 + t];
        ldsL[t] = 1.0f / L;
    }

    f32x4 acc[4];
#pragma unroll
    for (int j = 0; j < 4; ++j) acc[j] = f32x4{0.f, 0.f, 0.f, 0.f};

#pragma unroll
    for (int c = 0; c < CHUNKS; ++c) {
        const float* src = Opart + (size_t)(c * NTOK + r0) * 128;
#pragma unroll
        for (int j = 0; j < 4; ++j) {
            f32x4 v = *reinterpret_cast<const f32x4*>(src + j * 1024 + t * 4);
            acc[j] += v;
        }
    }
    __syncthreads();   // ldsL ready

#pragma unroll
    for (int j = 0; j < 4; ++j) {
        int flat = j * 1024 + t * 4;
        int row = flat >> 7, col = flat & 127;
        float sc = ldsL[row];
        u32x2 wv;
        wv[0] = pk_bf16(acc[j][0] * sc, acc[j][1] * sc);
        wv[1] = pk_bf16(acc[j][2] * sc, acc[j][3] * sc);
        *reinterpret_cast<u32x2*>(ldsO + row * 136 + col) = wv;
    }
    __syncthreads();

    // GEMM: 32 rows x 128 @ Wo^T; wave w -> output cols [w*32, w*32+32)
    int w = t >> 6, lane = t & 63;
    int l31 = lane & 31, hi = lane >> 5;

    bf16x8 af[8];
#pragma unroll
    for (int ks = 0; ks < 8; ++ks)
        af[ks] = ld_frag(ldsO + l31 * 136 + ks * 16 + hi * 8);

    f32x16 acc2;
#pragma unroll
    for (int r = 0; r < 16; ++r) acc2[r] = 0.f;

#pragma unroll
    for (int ks = 0; ks < 8; ++ks) {
        bf16x8 bfw = cvt_frag(Wo + (w * 32 + l31) * 128 + ks * 16 + hi * 8);
        acc2 = __builtin_amdgcn_mfma_f32_32x32x16_bf16(af[ks], bfw, acc2, 0, 0, 0);
    }

    float bb = bo[w * 32 + l31];
#pragma unroll
    for (int r = 0; r < 16; ++r) {
        int m = (r & 3) + 8 * (r >> 2) + 4 * hi;
        out[(size_t)(r0 + m) * 128 + w * 32 + l31] = acc2[r] + bb;
    }
}

// ------------------------------------------------------------------- launcher
extern "C" void kernel_launch(void* const* d_in, const int* in_sizes, int n_in,
                              void* d_out, int out_size, void* d_ws, size_t ws_size,
                              hipStream_t stream)
{
    const float* x  = (const float*)d_in[0];
    const float* Wq = (const float*)d_in[1];
    const float* bq = (const float*)d_in[2];
    const float* Wk = (const float*)d_in[3];
    const float* bk = (const float*)d_in[4];
    const float* Wv = (const float*)d_in[5];
    const float* bv = (const float*)d_in[6];
    const float* Wo = (const float*)d_in[7];
    const float* bo = (const float*)d_in[8];

    char* ws = (char*)d_ws;
    const size_t MB = 1024 * 1024;
    us16* Qb  = (us16*)(ws + 0 * MB);                   // 2 MB
    us16* Kb  = (us16*)(ws + 2 * MB);                   // 2 MB
    us16* Vt  = (us16*)(ws + 4 * MB);                   // 2 MB
    float* Lp = (float*)(ws + 6 * MB);                  // 256 KB
    float* Op = (float*)(ws + 7 * MB);                  // 32 MB
    // total ws use: 39 MB

    proj_qkv<<<384, 256, 0, stream>>>(x, Wq, bq, Wk, bk, Wv, bv, Qb, Kb, Vt);
    attn<<<256, 512, 0, stream>>>(Qb, Kb, Vt, Op, Lp);
    combine_proj<<<256, 256, 0, stream>>>(Op, Lp, Wo, bo, (float*)d_out);
}